// Round 1
// baseline (343.869 us; speedup 1.0000x reference)
//
#include <hip/hip_runtime.h>
#include <hip/hip_bf16.h>

#define BATCH 8
#define NDIM  2048
#define MDIM  2048
#define CDIM  128

typedef __attribute__((ext_vector_type(8))) short bf16x8;
typedef __attribute__((ext_vector_type(4))) float f32x4;

__device__ __forceinline__ float bf2f(unsigned int u16){
    union { unsigned int u; float f; } v; v.u = u16 << 16; return v.f;
}
__device__ __forceinline__ unsigned int f2bf(float f){
    union { float f; unsigned int u; } v; v.f = f;
    unsigned int u = v.u;
    u += 0x7FFFu + ((u >> 16) & 1u);   // round-to-nearest-even
    return u >> 16;
}

__global__ void ws_init_kernel(float* wsf){
    wsf[0] = 0.0f;          // loss numerator
    ((int*)wsf)[1] = 0;     // mask count
}

__global__ void finalize_kernel(const float* wsf, float* out){
    out[0] = wsf[0] / (float)(((const int*)wsf)[1]);
}

__global__ __launch_bounds__(256, 2) void cossim_bce_main(
    const int*  __restrict__ zp,
    const float* __restrict__ x1,
    const float* __restrict__ x2,
    const float* __restrict__ tparm,
    const float* __restrict__ bparm,
    float* __restrict__ out,
    float* __restrict__ wsf)
{
    // 64 KB LDS: two 128x128 bf16 tiles, XOR-swizzled (16B-chunk ^ row&7)
    __shared__ unsigned short lA[128*128];
    __shared__ unsigned short lB[128*128];

    const int t  = threadIdx.x;
    const int bx = blockIdx.x;   // M tile
    const int by = blockIdx.y;   // N tile
    const int bz = blockIdx.z;   // batch

    const float tv = *tparm;
    const float bv = *bparm;

    const float* x1base = x1 + ((size_t)(bz*NDIM) + by*128) * CDIM;
    const float* x2base = x2 + ((size_t)(bz*MDIM) + bx*128) * CDIM;

    // ---- stage: f32 -> bf16, coalesced global loads, swizzled LDS writes ----
    #pragma unroll
    for (int i = 0; i < 8; ++i){
        int chunk = i*256 + t;       // 2048 16B-chunks per tile
        int row = chunk >> 4;        // 0..127
        int pos = chunk & 15;        // 16B chunk within row
        int sw  = pos ^ (row & 7);   // bank-conflict swizzle
        {
            const float* p = x1base + row*CDIM + pos*8;
            float4 a = *(const float4*)p;
            float4 b = *(const float4*)(p + 4);
            uint4 pk;
            pk.x = f2bf(a.x) | (f2bf(a.y) << 16);
            pk.y = f2bf(a.z) | (f2bf(a.w) << 16);
            pk.z = f2bf(b.x) | (f2bf(b.y) << 16);
            pk.w = f2bf(b.z) | (f2bf(b.w) << 16);
            ((uint4*)lA)[row*16 + sw] = pk;
        }
        {
            const float* p = x2base + row*CDIM + pos*8;
            float4 a = *(const float4*)p;
            float4 b = *(const float4*)(p + 4);
            uint4 pk;
            pk.x = f2bf(a.x) | (f2bf(a.y) << 16);
            pk.y = f2bf(a.z) | (f2bf(a.w) << 16);
            pk.z = f2bf(b.x) | (f2bf(b.y) << 16);
            pk.w = f2bf(b.z) | (f2bf(b.w) << 16);
            ((uint4*)lB)[row*16 + sw] = pk;
        }
    }
    __syncthreads();

    const int lane = t & 63;
    const int w    = t >> 6;
    const int wrow = (w >> 1) * 64;  // wave output row offset
    const int wcol = (w & 1) * 64;   // wave output col offset
    const int quad = lane >> 4;      // 0..3 (k-group for A/B frags)
    const int l16  = lane & 15;      // row (A) / col (B)

    f32x4 acc[4][4];
    #pragma unroll
    for (int m = 0; m < 4; ++m)
        #pragma unroll
        for (int n = 0; n < 4; ++n)
            acc[m][n] = (f32x4){0.f, 0.f, 0.f, 0.f};

    // ---- MFMA: K=128 in 4 steps of 32 ----
    #pragma unroll
    for (int kk = 0; kk < 4; ++kk){
        const int kc = kk*4 + quad;          // 16B k-chunk index
        bf16x8 afr[4], bfr[4];
        #pragma unroll
        for (int m = 0; m < 4; ++m){
            int row = wrow + m*16 + l16;
            afr[m] = ((const bf16x8*)lA)[row*16 + (kc ^ (row & 7))];
        }
        #pragma unroll
        for (int n = 0; n < 4; ++n){
            int row = wcol + n*16 + l16;
            bfr[n] = ((const bf16x8*)lB)[row*16 + (kc ^ (row & 7))];
        }
        #pragma unroll
        for (int m = 0; m < 4; ++m)
            #pragma unroll
            for (int n = 0; n < 4; ++n)
                acc[m][n] = __builtin_amdgcn_mfma_f32_16x16x32_bf16(
                                afr[m], bfr[n], acc[m][n], 0, 0, 0);
    }

    // ---- row/col reciprocal norms from the bf16 tiles (one row per thread) ----
    float invn;
    {
        int row = t & 127;
        const unsigned short* src = (t < 128) ? lA : lB;
        float s = 0.f;
        #pragma unroll
        for (int c = 0; c < 16; ++c){
            uint4 v = ((const uint4*)src)[row*16 + (c ^ (row & 7))];
            float f0 = bf2f(v.x & 0xffffu), f1 = bf2f(v.x >> 16);
            float f2 = bf2f(v.y & 0xffffu), f3 = bf2f(v.y >> 16);
            float f4 = bf2f(v.z & 0xffffu), f5 = bf2f(v.z >> 16);
            float f6 = bf2f(v.w & 0xffffu), f7 = bf2f(v.w >> 16);
            s += f0*f0 + f1*f1 + f2*f2 + f3*f3 + f4*f4 + f5*f5 + f6*f6 + f7*f7;
        }
        invn = 1.0f / sqrtf(fmaxf(s, 1e-16f));
    }
    __syncthreads();                 // all tile reads done
    float* nsh = (float*)lA;         // reuse LDS: [0..127]=1/n1, [128..255]=1/n2
    nsh[t] = invn;
    __syncthreads();

    // ---- epilogue: cos, mask, NLL ----
    float* cosOut  = out + 1;
    float* maskOut = out + 1 + (size_t)BATCH*NDIM*MDIM;
    const size_t batchOff = (size_t)bz * NDIM * MDIM;
    const size_t rowBase  = (size_t)(by*128) * MDIM + (size_t)(bx*128);

    float lnum = 0.f;
    int   lcnt = 0;
    #pragma unroll
    for (int m = 0; m < 4; ++m){
        #pragma unroll
        for (int r = 0; r < 4; ++r){
            int rowL = wrow + m*16 + quad*4 + r;
            float in1 = nsh[rowL];
            size_t rbase = batchOff + rowBase + (size_t)rowL * MDIM;
            #pragma unroll
            for (int n = 0; n < 4; ++n){
                int colL = wcol + n*16 + l16;
                float in2 = nsh[128 + colL];
                float cs  = acc[m][n][r] * in1 * in2;
                size_t idx = rbase + colL;
                int zv = zp[idx];
                cosOut[idx]  = cs;
                maskOut[idx] = zv ? 1.0f : 0.0f;
                if (zv){
                    float y  = (float)zv * (tv*cs - bv);
                    float xm = -y;
                    // softplus(-y), numerically stable
                    float nll = fmaxf(xm, 0.f) + log1pf(__expf(-fabsf(xm)));
                    lnum += nll;
                    lcnt += 1;
                }
            }
        }
    }

    // wave reduction, one atomic pair per wave
    #pragma unroll
    for (int off = 32; off > 0; off >>= 1){
        lnum += __shfl_down(lnum, off);
        lcnt += __shfl_down(lcnt, off);
    }
    if (lane == 0){
        atomicAdd(wsf, lnum);
        atomicAdd((int*)wsf + 1, lcnt);
    }
}

extern "C" void kernel_launch(void* const* d_in, const int* in_sizes, int n_in,
                              void* d_out, int out_size, void* d_ws, size_t ws_size,
                              hipStream_t stream) {
    const int*   zp = (const int*)  d_in[0];
    const float* x1 = (const float*)d_in[1];
    const float* x2 = (const float*)d_in[2];
    const float* tp = (const float*)d_in[3];
    const float* bp = (const float*)d_in[4];
    float* out = (float*)d_out;
    float* wsf = (float*)d_ws;

    ws_init_kernel<<<1, 1, 0, stream>>>(wsf);
    dim3 grid(MDIM/128, NDIM/128, BATCH);
    cossim_bce_main<<<grid, 256, 0, stream>>>(zp, x1, x2, tp, bp, out, wsf);
    finalize_kernel<<<1, 1, 0, stream>>>(wsf, out);
}